// Round 1
// baseline (210.973 us; speedup 1.0000x reference)
//
#include <hip/hip_runtime.h>
#include <hip/hip_bf16.h>
#include <math.h>

#define B 4
#define L 2048
#define D 256
#define H 8
#define HD 32
#define SCALE 0.17677669529663687f

typedef __attribute__((ext_vector_type(8))) short short8;
typedef __attribute__((ext_vector_type(4))) float f32x4;

__device__ inline short f2bf(float x) {
  union { float f; unsigned u; } c; c.f = x;
  unsigned r = (c.u + 0x7FFFu + ((c.u >> 16) & 1u)) >> 16;
  return (short)r;
}

// ---------------- Kernel 1: qkv = x @ Wqkv, head-split bf16 outputs ----------
// x: [8192, 256] f32, w: [256, 768] f32
// qb/kb/vb: [B*H, L, HD] bf16
__global__ __launch_bounds__(64) void qkv_gemm(const float* __restrict__ x,
                                               const float* __restrict__ w,
                                               short* __restrict__ qb,
                                               short* __restrict__ kb,
                                               short* __restrict__ vb) {
  int bid = blockIdx.x;
  int nt = bid % 48;    // 768 / 16 n-tiles
  int mt = bid / 48;    // 8192 / 64 m-blocks
  int m0 = mt * 64, n0 = nt * 16;
  int l = threadIdx.x;
  int ra = l & 15, g = l >> 4;

  f32x4 acc[4] = {};
  for (int k0 = 0; k0 < 256; k0 += 32) {
    int kk = k0 + g * 8;
    short8 bfrag;
#pragma unroll
    for (int j = 0; j < 8; ++j) bfrag[j] = f2bf(w[(kk + j) * 768 + n0 + ra]);
#pragma unroll
    for (int m = 0; m < 4; ++m) {
      const float* ap = x + (m0 + m * 16 + ra) * 256 + kk;
      short8 afrag;
#pragma unroll
      for (int j = 0; j < 8; ++j) afrag[j] = f2bf(ap[j]);
      acc[m] = __builtin_amdgcn_mfma_f32_16x16x32_bf16(afrag, bfrag, acc[m], 0, 0, 0);
    }
  }

  int n = n0 + ra;
  int which = n >> 8;   // 0=q 1=k 2=v
  int c = n & 255;
  int h = c >> 5, d = c & 31;
  short* dst = which == 0 ? qb : (which == 1 ? kb : vb);
#pragma unroll
  for (int m = 0; m < 4; ++m) {
#pragma unroll
    for (int r = 0; r < 4; ++r) {
      int mm = m0 + m * 16 + g * 4 + r;
      int b = mm >> 11, lpos = mm & 2047;
      dst[((b * H + h) * L + lpos) * HD + d] = f2bf(acc[m][r]);
    }
  }
}

// ---------------- Kernel 2: flash attention, 1 wave / 16 q-rows -------------
__global__ __launch_bounds__(64) void attn_fwd(const short* __restrict__ qb,
                                               const short* __restrict__ kb,
                                               const short* __restrict__ vb,
                                               const float* __restrict__ bias,
                                               short* __restrict__ ob) {
  int bid = blockIdx.x;
  int qt = bid & 127;   // L/16 q-tiles
  int bh = bid >> 7;    // 0..31
  int q0 = qt * 16;
  int l = threadIdx.x;
  int ra = l & 15, g = l >> 4;

  __shared__ float p_lds[16][32];

  short8 aq = *reinterpret_cast<const short8*>(qb + (bh * L + q0 + ra) * HD + g * 8);

  f32x4 o0 = {}, o1 = {};
  float mrun[4], lsum[4];
#pragma unroll
  for (int r = 0; r < 4; ++r) { mrun[r] = -1e30f; lsum[r] = 0.f; }
  f32x4 zero = {};

  for (int kv = 0; kv < L; kv += 32) {
    short8 bk0 = *reinterpret_cast<const short8*>(kb + (bh * L + kv + ra) * HD + g * 8);
    short8 bk1 = *reinterpret_cast<const short8*>(kb + (bh * L + kv + 16 + ra) * HD + g * 8);
    f32x4 s0 = __builtin_amdgcn_mfma_f32_16x16x32_bf16(aq, bk0, zero, 0, 0, 0);
    f32x4 s1 = __builtin_amdgcn_mfma_f32_16x16x32_bf16(aq, bk1, zero, 0, 0, 0);

#pragma unroll
    for (int r = 0; r < 4; ++r) {
      int qr = g * 4 + r;
      float v0 = s0[r] * SCALE + bias[(q0 + qr) * L + kv + ra];
      float v1 = s1[r] * SCALE + bias[(q0 + qr) * L + kv + 16 + ra];
      float mx = fmaxf(v0, v1);
      mx = fmaxf(mx, __shfl_xor(mx, 1));
      mx = fmaxf(mx, __shfl_xor(mx, 2));
      mx = fmaxf(mx, __shfl_xor(mx, 4));
      mx = fmaxf(mx, __shfl_xor(mx, 8));
      float mnew = fmaxf(mrun[r], mx);
      float alpha = __expf(mrun[r] - mnew);
      float p0 = __expf(v0 - mnew);
      float p1 = __expf(v1 - mnew);
      float rs = p0 + p1;
      rs += __shfl_xor(rs, 1);
      rs += __shfl_xor(rs, 2);
      rs += __shfl_xor(rs, 4);
      rs += __shfl_xor(rs, 8);
      lsum[r] = lsum[r] * alpha + rs;
      mrun[r] = mnew;
      o0[r] *= alpha;
      o1[r] *= alpha;
      p_lds[qr][ra] = p0;
      p_lds[qr][16 + ra] = p1;
    }
    __syncthreads();

    short8 pa;
    const float* pr = &p_lds[ra][g * 8];
#pragma unroll
    for (int j = 0; j < 8; ++j) pa[j] = f2bf(pr[j]);

    short8 bv0, bv1;
#pragma unroll
    for (int j = 0; j < 8; ++j) {
      bv0[j] = vb[(bh * L + kv + g * 8 + j) * HD + ra];
      bv1[j] = vb[(bh * L + kv + g * 8 + j) * HD + 16 + ra];
    }
    o0 = __builtin_amdgcn_mfma_f32_16x16x32_bf16(pa, bv0, o0, 0, 0, 0);
    o1 = __builtin_amdgcn_mfma_f32_16x16x32_bf16(pa, bv1, o1, 0, 0, 0);
    __syncthreads();
  }

  int b = bh >> 3, h = bh & 7;
#pragma unroll
  for (int r = 0; r < 4; ++r) {
    float inv = 1.0f / lsum[r];
    int row = (b * L + q0 + g * 4 + r) * D + h * HD;
    ob[row + ra] = f2bf(o0[r] * inv);
    ob[row + 16 + ra] = f2bf(o1[r] * inv);
  }
}

// ---------------- Kernel 3: out = O @ Wout ----------------------------------
// ob: [8192, 256] bf16, w: [256, 256] f32, out: [8192, 256] f32
__global__ __launch_bounds__(64) void out_gemm(const short* __restrict__ ob,
                                               const float* __restrict__ w,
                                               float* __restrict__ out) {
  int bid = blockIdx.x;
  int nt = bid % 16, mt = bid / 16;
  int m0 = mt * 64, n0 = nt * 16;
  int l = threadIdx.x, ra = l & 15, g = l >> 4;

  f32x4 acc[4] = {};
  for (int k0 = 0; k0 < 256; k0 += 32) {
    int kk = k0 + g * 8;
    short8 bfrag;
#pragma unroll
    for (int j = 0; j < 8; ++j) bfrag[j] = f2bf(w[(kk + j) * 256 + n0 + ra]);
#pragma unroll
    for (int m = 0; m < 4; ++m) {
      short8 afrag = *reinterpret_cast<const short8*>(ob + (m0 + m * 16 + ra) * 256 + kk);
      acc[m] = __builtin_amdgcn_mfma_f32_16x16x32_bf16(afrag, bfrag, acc[m], 0, 0, 0);
    }
  }
#pragma unroll
  for (int m = 0; m < 4; ++m)
#pragma unroll
    for (int r = 0; r < 4; ++r)
      out[(m0 + m * 16 + g * 4 + r) * 256 + n0 + ra] = acc[m][r];
}

extern "C" void kernel_launch(void* const* d_in, const int* in_sizes, int n_in,
                              void* d_out, int out_size, void* d_ws, size_t ws_size,
                              hipStream_t stream) {
  const float* x    = (const float*)d_in[0];
  const float* bias = (const float*)d_in[1];
  const float* wqkv = (const float*)d_in[2];
  const float* wout = (const float*)d_in[3];
  float* out = (float*)d_out;

  short* qb = (short*)d_ws;           // [B*H, L, HD] bf16 = 2M elems
  short* kb = qb + B * L * D;
  short* vb = kb + B * L * D;
  short* ob = vb + B * L * D;         // [B*L, D] bf16

  qkv_gemm<<<dim3(6144), dim3(64), 0, stream>>>(x, wqkv, qb, kb, vb);
  attn_fwd<<<dim3(4096), dim3(64), 0, stream>>>(qb, kb, vb, bias, ob);
  out_gemm<<<dim3(2048), dim3(64), 0, stream>>>(ob, wout, out);
}